// Round 14
// baseline (663.815 us; speedup 1.0000x reference)
//
#include <hip/hip_runtime.h>
#include <cstdint>

// out[s,b,m,n] = sum_k (x+66)*0.03 * (y-160)*0.025,  S=7 B=8 M=K=N=1024
// y' = y-128; x, y' exact int8. i8 MFMA (int32-exact):
//   out = 7.5e-4 * ( S' - 32*Rx[m] + 66*Cy[n] - 10813440 ),  S' = sum x*y'
// FUSED GEMM (prep_x eliminated): 256x256, 8 waves, BK=64B, R12 4-phase skeleton.
//   A: fp32 -> asm global_load x8 (issued 1 tile ahead at p3) -> pack i8 (+row
//      sums Rx on the fly) -> ds_write into As ring-2, swizzled write address.
//   B: yt i8 via global_load_lds, ring-3, inverse-source swizzle (verified).
//   All loop VMEM is manually counted: tile-start vmcnt(10), p3 vmcnt(2).

#define NG 56

typedef int   v4i  __attribute__((ext_vector_type(4)));
typedef int   v16i __attribute__((ext_vector_type(16)));

#define GLOAD16(g, l) __builtin_amdgcn_global_load_lds( \
    (const __attribute__((address_space(1))) void*)(g), \
    (__attribute__((address_space(3))) void*)(l), 16, 0, 0)

#define MFMA_I8(a, b, c) __builtin_amdgcn_mfma_i32_32x32x32_i8(a, b, c, 0, 0, 0)

typedef __attribute__((address_space(3))) const unsigned char* lds_cptr;

__device__ __forceinline__ v4i lds_read16(lds_cptr p) {
    v4i d;
    asm volatile("ds_read_b128 %0, %1" : "=v"(d) : "v"(p));
    return d;
}

// int-bits float4 -> 4 i8 bytes (exponent-pin), accumulate row sum
__device__ __forceinline__ unsigned pk(v4i v, float& s) {
    float x0 = __int_as_float(v[0]), x1 = __int_as_float(v[1]);
    float x2 = __int_as_float(v[2]), x3 = __int_as_float(v[3]);
    s += (x0 + x1) + (x2 + x3);
    unsigned b0 = __float_as_uint(x0 + 8388736.0f);  // 2^23 + 128
    unsigned b1 = __float_as_uint(x1 + 8388736.0f);
    unsigned b2 = __float_as_uint(x2 + 8388736.0f);
    unsigned b3 = __float_as_uint(x3 + 8388736.0f);
    return ((b0 & 0xFFu) | ((b1 & 0xFFu) << 8) | ((b2 & 0xFFu) << 16) | ((b3 & 0xFFu) << 24))
           ^ 0x80808080u;
}

// ---- prepass: y [b][k][n] -> yt [b][n][k] i8 (= y-128), + col sums Cy ----
__global__ __launch_bounds__(256) void k_prep_y(const float* __restrict__ y,
                                                unsigned char* __restrict__ yt,
                                                float* __restrict__ cy) {
    __shared__ float tile[64][65];
    __shared__ float csum[4][64];
    int b  = blockIdx.x >> 8;
    int t  = blockIdx.x & 255;
    int kt = (t >> 4) * 64, nt = (t & 15) * 64;
    int tx = threadIdx.x & 63;
    int ty = threadIdx.x >> 6;
    const float* src = y + ((size_t)b << 20) + (size_t)kt * 1024 + nt;
    float part = 0.f;
#pragma unroll
    for (int r = 0; r < 16; ++r) {
        int kk = r * 4 + ty;
        float v = src[(size_t)kk * 1024 + tx];
        tile[kk][tx] = v;
        part += v;
    }
    csum[ty][tx] = part;
    __syncthreads();
    if (threadIdx.x < 64) {
        float s = csum[0][tx] + csum[1][tx] + csum[2][tx] + csum[3][tx];
        atomicAdd(&cy[b * 1024 + nt + tx], s);
    }
    int ky = threadIdx.x & 15;
    int ny = threadIdx.x >> 4;
#pragma unroll
    for (int r = 0; r < 4; ++r) {
        int nn = r * 16 + ny;
        unsigned b0 = __float_as_uint(tile[ky * 4 + 0][nn] + 8388608.0f);
        unsigned b1 = __float_as_uint(tile[ky * 4 + 1][nn] + 8388608.0f);
        unsigned b2 = __float_as_uint(tile[ky * 4 + 2][nn] + 8388608.0f);
        unsigned b3 = __float_as_uint(tile[ky * 4 + 3][nn] + 8388608.0f);
        unsigned p = ((b0 & 0xFFu) | ((b1 & 0xFFu) << 8) | ((b2 & 0xFFu) << 16) |
                      ((b3 & 0xFFu) << 24)) ^ 0x80808080u;
        *(unsigned*)&yt[((size_t)b << 20) + (size_t)(nt + nn) * 1024 + kt + ky * 4] = p;
    }
}

// ---- fused GEMM ----
__global__ __launch_bounds__(512, 2) void k_gemm(const float* __restrict__ xf,
                                                 const unsigned char* __restrict__ yt,
                                                 const float* __restrict__ cy,
                                                 float* __restrict__ out) {
    __shared__ __align__(16) unsigned char As[2][256 * 64];   // 32 KB (A i8, ring-2)
    __shared__ __align__(16) unsigned char Bs[3][256 * 64];   // 48 KB (B i8, ring-3)

    int bid = blockIdx.x;                         // 896 = 8 * 112, bijective XCD swz
    int wg  = (bid & 7) * 112 + (bid >> 3);
    int g   = wg >> 4;
    int t   = wg & 15;
    int m0  = (t >> 2) * 256, n0 = (t & 3) * 256;
    int b   = g & 7;

    int tid = threadIdx.x, lane = tid & 63, w = tid >> 6;
    int wm = w >> 2, wn = w & 3;                  // 2M x 4N wave grid

    // ---- A reg-stage constants: thread owns rows r0 and r0+128, 16-elem chunk cg
    int r0   = tid >> 2;
    int cg   = tid & 3;
    int wkey = (tid >> 3) & 3;                    // = (r0>>1)&3
    int wadr0 = r0 * 64 + ((cg ^ wkey) * 16);     // swizzled ds_write addr
    int wadr1 = wadr0 + 8192;                     // rows +128
    const float* Af0 = xf + (size_t)g * 1048576 + (size_t)(m0 + r0) * 1024 + cg * 16;
    const float* Af1 = Af0 + 131072;              // +128 rows

    // ---- B staging (verified): inverse-source swizzle, linear LDS dest
    size_t soff0 = (size_t)r0 * 1024 + (size_t)((cg ^ wkey) * 16);
    size_t soff1 = soff0 + 131072;
    int bdst0 = (tid & ~63) * 16;
    int bdst1 = 8192 + bdst0;
    const unsigned char* Bb = yt + ((size_t)b << 20) + (size_t)n0 * 1024;

    // ---- fragment read addresses (verified): key = (lane>>1)&3
    int arow = lane & 31, hi = lane >> 5, key = (lane >> 1) & 3;
    int rA0 = (wm * 128 +  0 + arow) * 64;
    int rA1 = (wm * 128 + 32 + arow) * 64;
    int rA2 = (wm * 128 + 64 + arow) * 64;
    int rA3 = (wm * 128 + 96 + arow) * 64;
    int rB0 = (wn * 64 +  0 + arow) * 64;
    int rB1 = (wn * 64 + 32 + arow) * 64;
    int c0 = (hi ^ key) * 16;
    int c1 = ((2 + hi) ^ key) * 16;

    v16i acc[4][2];
#pragma unroll
    for (int i = 0; i < 4; ++i)
#pragma unroll
        for (int j = 0; j < 2; ++j)
#pragma unroll
            for (int q = 0; q < 16; ++q) acc[i][j][q] = 0;

    v4i fr0, fr1, fr2, fr3, fr4, fr5, fr6, fr7;   // in-flight A fp32 (1 tile)
    float rs0 = 0.f, rs1 = 0.f;                   // row-sum accumulators

#define LOADA(KT) do {                                                              \
    const float* _p0 = Af0 + (KT) * 64;                                             \
    const float* _p1 = Af1 + (KT) * 64;                                             \
    asm volatile("global_load_dwordx4 %0, %1, off"           : "=&v"(fr0) : "v"(_p0) : "memory"); \
    asm volatile("global_load_dwordx4 %0, %1, off offset:16" : "=&v"(fr1) : "v"(_p0) : "memory"); \
    asm volatile("global_load_dwordx4 %0, %1, off offset:32" : "=&v"(fr2) : "v"(_p0) : "memory"); \
    asm volatile("global_load_dwordx4 %0, %1, off offset:48" : "=&v"(fr3) : "v"(_p0) : "memory"); \
    asm volatile("global_load_dwordx4 %0, %1, off"           : "=&v"(fr4) : "v"(_p1) : "memory"); \
    asm volatile("global_load_dwordx4 %0, %1, off offset:16" : "=&v"(fr5) : "v"(_p1) : "memory"); \
    asm volatile("global_load_dwordx4 %0, %1, off offset:32" : "=&v"(fr6) : "v"(_p1) : "memory"); \
    asm volatile("global_load_dwordx4 %0, %1, off offset:48" : "=&v"(fr7) : "v"(_p1) : "memory"); \
} while (0)

#define PACKST(SLOT) do {                                                           \
    unsigned q0 = pk(fr0, rs0), q1 = pk(fr1, rs0), q2 = pk(fr2, rs0), q3 = pk(fr3, rs0); \
    v4i w0 = { (int)q0, (int)q1, (int)q2, (int)q3 };                                \
    *(v4i*)&As[SLOT][wadr0] = w0;                                                   \
    q0 = pk(fr4, rs1); q1 = pk(fr5, rs1); q2 = pk(fr6, rs1); q3 = pk(fr7, rs1);     \
    v4i w1 = { (int)q0, (int)q1, (int)q2, (int)q3 };                                \
    *(v4i*)&As[SLOT][wadr1] = w1;                                                   \
} while (0)

#define STAGEB(SLOT, KT) do {                                                       \
    GLOAD16(Bb + soff0 + (size_t)(KT) * 64, &Bs[SLOT][bdst0]);                      \
    GLOAD16(Bb + soff1 + (size_t)(KT) * 64, &Bs[SLOT][bdst1]);                      \
} while (0)

#define SB0 __builtin_amdgcn_sched_barrier(0)
#define LGKM(N) asm volatile("s_waitcnt lgkmcnt(" #N ")" ::: "memory")

#define MFMA4(I, A0_, A1_, B0_, B1_) do {                 \
    __builtin_amdgcn_s_setprio(1);                        \
    acc[I][0]     = MFMA_I8(A0_, B0_, acc[I][0]);         \
    acc[I][1]     = MFMA_I8(A0_, B1_, acc[I][1]);         \
    acc[I + 1][0] = MFMA_I8(A1_, B0_, acc[I + 1][0]);     \
    acc[I + 1][1] = MFMA_I8(A1_, B1_, acc[I + 1][1]);     \
    __builtin_amdgcn_s_setprio(0);                        \
} while (0)

// VMST/VMP3 passed as full asm statements
#define VMW(N) asm volatile("s_waitcnt vmcnt(" #N ")" ::: "memory")

#define TILE(SA, SBr, SBW, VMST, VMP3, DOB, DOA, DOP, KT) do {                      \
    lds_cptr ap = (lds_cptr)&As[SA][0];                                             \
    lds_cptr bp = (lds_cptr)&Bs[SBr][0];                                            \
    /* p0 */                                                                        \
    VMST;                                                                           \
    __builtin_amdgcn_s_barrier(); SB0;                                              \
    v4i fa0 = lds_read16(ap + rA0 + c0);                                            \
    v4i fa1 = lds_read16(ap + rA1 + c0);                                            \
    v4i fb0 = lds_read16(bp + rB0 + c0);                                            \
    v4i fb1 = lds_read16(bp + rB1 + c0);                                            \
    v4i ga0 = lds_read16(ap + rA2 + c0);                                            \
    v4i ga1 = lds_read16(ap + rA3 + c0);                                            \
    LGKM(2); SB0;                                                                   \
    MFMA4(0, fa0, fa1, fb0, fb1);                                                   \
    /* p1 */                                                                        \
    __builtin_amdgcn_s_barrier(); SB0;                                              \
    v4i ha0 = lds_read16(ap + rA0 + c1);                                            \
    v4i ha1 = lds_read16(ap + rA1 + c1);                                            \
    v4i hb0 = lds_read16(bp + rB0 + c1);                                            \
    v4i hb1 = lds_read16(bp + rB1 + c1);                                            \
    LGKM(4); SB0;                                                                   \
    MFMA4(2, ga0, ga1, fb0, fb1);                                                   \
    /* p2 */                                                                        \
    __builtin_amdgcn_s_barrier(); SB0;                                              \
    v4i ia0 = lds_read16(ap + rA2 + c1);                                            \
    v4i ia1 = lds_read16(ap + rA3 + c1);                                            \
    if (DOB) { STAGEB(SBW, (KT) + 2); }                                             \
    LGKM(2); SB0;                                                                   \
    MFMA4(0, ha0, ha1, hb0, hb1);                                                   \
    /* p3 */                                                                        \
    __builtin_amdgcn_s_barrier(); SB0;                                              \
    VMP3; SB0;                                                                      \
    if (DOP) { PACKST(((KT) + 1) & 1); }                                            \
    if (DOA) { LOADA((KT) + 2); }                                                   \
    LGKM(0); SB0;                                                                   \
    MFMA4(2, ia0, ia1, hb0, hb1);                                                   \
} while (0)

    // ---- prologue: A(0) regs; B(0),B(1) staged; pack A(0)->slot0; issue A(1)
    LOADA(0); SB0;
    STAGEB(0, 0);
    STAGEB(1, 1); SB0;
    VMW(4); SB0;                 // drain A(0) (B0,B1 younger = 4)
    PACKST(0);
    LOADA(1); SB0;
    LGKM(0); SB0;                // As slot0 writes visible before tile0 barrier

    // ---- main: T = 0..11 (2 rounds of the period-6 slot pattern)
#pragma unroll 1
    for (int rr = 0; rr < 2; ++rr) {
        int KT = rr * 6;
        TILE(0, 0, 2, VMW(10), VMW(2), 1, 1, 1, (KT + 0));
        TILE(1, 1, 0, VMW(10), VMW(2), 1, 1, 1, (KT + 1));
        TILE(0, 2, 1, VMW(10), VMW(2), 1, 1, 1, (KT + 2));
        TILE(1, 0, 2, VMW(10), VMW(2), 1, 1, 1, (KT + 3));
        TILE(0, 1, 0, VMW(10), VMW(2), 1, 1, 1, (KT + 4));
        TILE(1, 2, 1, VMW(10), VMW(2), 1, 1, 1, (KT + 5));
    }
    // T=12,13 (full), T=14 (no B/A issue), T=15 (drain)
    TILE(0, 0, 2, VMW(10), VMW(2), 1, 1, 1, 12);
    TILE(1, 1, 0, VMW(10), VMW(2), 1, 1, 1, 13);
    TILE(0, 2, 0, VMW(10), VMW(0), 0, 0, 1, 14);
    TILE(1, 0, 0, VMW(0),  (void)0, 0, 0, 0, 15);
#undef TILE

    // ---- row sums: 4 lanes per row -> rxs in LDS (reuse As)
    rs0 += __shfl_xor(rs0, 1); rs0 += __shfl_xor(rs0, 2);
    rs1 += __shfl_xor(rs1, 1); rs1 += __shfl_xor(rs1, 2);
    float* rxs = (float*)&As[0][0];
    __syncthreads();
    if ((tid & 3) == 0) { rxs[r0] = rs0; rxs[r0 + 128] = rs1; }
    __syncthreads();

    // ---- epilogue: out = 7.5e-4 * (S' - 32*Rx + 66*Cy - 10813440)
    const float* cyp = cy + b * 1024 + n0 + wn * 64;
    float* og = out + (size_t)g * 1048576 + (size_t)(m0 + wm * 128) * 1024 + n0 + wn * 64;
    int col = lane & 31, r4 = hi * 4;
#pragma unroll
    for (int fi = 0; fi < 4; ++fi)
#pragma unroll
        for (int fj = 0; fj < 2; ++fj) {
            int cc = fj * 32 + col;
            float cv = cyp[cc];
            v16i v = acc[fi][fj];
#pragma unroll
            for (int q = 0; q < 16; ++q) {
                int rl = (q & 3) + 8 * (q >> 2) + r4;
                float rxv = rxs[wm * 128 + fi * 32 + rl];
                og[(size_t)(fi * 32 + rl) * 1024 + cc] =
                    7.5e-4f * ((float)v[q] - 32.0f * rxv + 66.0f * cv - 10813440.0f);
            }
        }
#undef LOADA
#undef PACKST
#undef STAGEB
#undef MFMA4
#undef LGKM
#undef VMW
#undef SB0
}

// ---- emergency fallback ----
__global__ void k_naive(const float* __restrict__ x, const float* __restrict__ y,
                        float* __restrict__ out) {
    int g = blockIdx.z, b = g & 7;
    int tx = threadIdx.x, ty = threadIdx.y;
    int m = blockIdx.y * 16 + ty, n = blockIdx.x * 16 + tx;
    __shared__ float a[16][17], bs[16][17];
    float s = 0.f;
    for (int kt = 0; kt < 64; ++kt) {
        a[ty][tx]  = x[(size_t)g * 1048576 + (size_t)m * 1024 + kt * 16 + tx];
        bs[ty][tx] = y[(size_t)b * 1048576 + (size_t)(kt * 16 + ty) * 1024 + n];
        __syncthreads();
#pragma unroll
        for (int j = 0; j < 16; ++j)
            s += ((a[ty][j] + 66.0f) * 0.03f) * ((bs[j][tx] - 160.0f) * 0.025f);
        __syncthreads();
    }
    out[(size_t)g * 1048576 + (size_t)m * 1024 + n] = s;
}

extern "C" void kernel_launch(void* const* d_in, const int* in_sizes, int n_in,
                              void* d_out, int out_size, void* d_ws, size_t ws_size,
                              hipStream_t stream) {
    const float* x = (const float*)d_in[0];
    const float* y = (const float*)d_in[1];
    float* out = (float*)d_out;

    const size_t CY_OFF = 0;                  // 32 KB
    const size_t YT_OFF = 262144;             // 8 MB i8 yt
    const size_t NEED   = YT_OFF + 8388608ull;

    if (ws_size >= NEED) {
        float* cy         = (float*)((char*)d_ws + CY_OFF);
        unsigned char* yt = (unsigned char*)((char*)d_ws + YT_OFF);
        hipMemsetAsync(cy, 0, 32768, stream);
        k_prep_y<<<2048, 256, 0, stream>>>(y, yt, cy);
        k_gemm<<<NG * 16, 512, 0, stream>>>(x, yt, cy, out);
    } else {
        dim3 grid(64, 64, NG), blk(16, 16);
        k_naive<<<grid, blk, 0, stream>>>(x, y, out);
    }
}

// Round 15
// 564.209 us; speedup vs baseline: 1.1765x; 1.1765x over previous
//
#include <hip/hip_runtime.h>
#include <cstdint>

// out[s,b,m,n] = sum_k (x+66)*0.03 * (y-160)*0.025,  S=7 B=8 M=K=N=1024
// y' = y-128; x, y' exact int8. i8 MFMA (int32-exact):
//   out = 7.5e-4 * ( S' - 32*Rx[m] + 66*Cy[n] - 10813440 ),  S' = sum x*y'
// FUSED GEMM (no prep_x): 256x256, 8 waves, BK=64B, 4-phase skeleton.
//   A: fp32 global->reg in HALF-TILES (16 VGPR in flight) -> pack i8 (+Rx on the
//      fly) -> swizzled ds_write, As ring-2 (32KB).
//   B: yt i8 via global_load_lds, ring-3 (48KB), inverse-source swizzle.
//   vmcnt fully hand-counted: p1 vmcnt(4), p3 vmcnt(2); prologue vmcnt(6)
//   drains B(0) before first reads (R14 had a latent race here).
//   VGPR budget: acc128 + A-inflight 32 + frag/addr ~80 -> ~240 < 256 (no spill).

#define NG 56

typedef int v4i  __attribute__((ext_vector_type(4)));
typedef int v16i __attribute__((ext_vector_type(16)));

#define GLOAD16(g, l) __builtin_amdgcn_global_load_lds( \
    (const __attribute__((address_space(1))) void*)(g), \
    (__attribute__((address_space(3))) void*)(l), 16, 0, 0)

#define MFMA_I8(a, b, c) __builtin_amdgcn_mfma_i32_32x32x32_i8(a, b, c, 0, 0, 0)

typedef __attribute__((address_space(3))) const unsigned char* lds_cptr;

#define LDSR(D, P, OFF) \
    asm volatile("ds_read_b128 %0, %1 offset:" #OFF : "=v"(D) : "v"(P))

// int-bits float4 -> 4 i8 bytes (exponent-pin), accumulate row sum
__device__ __forceinline__ unsigned pk(v4i v, float& s) {
    float x0 = __int_as_float(v[0]), x1 = __int_as_float(v[1]);
    float x2 = __int_as_float(v[2]), x3 = __int_as_float(v[3]);
    s += (x0 + x1) + (x2 + x3);
    unsigned b0 = __float_as_uint(x0 + 8388736.0f);  // 2^23 + 128
    unsigned b1 = __float_as_uint(x1 + 8388736.0f);
    unsigned b2 = __float_as_uint(x2 + 8388736.0f);
    unsigned b3 = __float_as_uint(x3 + 8388736.0f);
    return ((b0 & 0xFFu) | ((b1 & 0xFFu) << 8) | ((b2 & 0xFFu) << 16) | ((b3 & 0xFFu) << 24))
           ^ 0x80808080u;
}

// ---- prepass: y [b][k][n] -> yt [b][n][k] i8 (= y-128), + col sums Cy ----
__global__ __launch_bounds__(256) void k_prep_y(const float* __restrict__ y,
                                                unsigned char* __restrict__ yt,
                                                float* __restrict__ cy) {
    __shared__ float tile[64][65];
    __shared__ float csum[4][64];
    int b  = blockIdx.x >> 8;
    int t  = blockIdx.x & 255;
    int kt = (t >> 4) * 64, nt = (t & 15) * 64;
    int tx = threadIdx.x & 63;
    int ty = threadIdx.x >> 6;
    const float* src = y + ((size_t)b << 20) + (size_t)kt * 1024 + nt;
    float part = 0.f;
#pragma unroll
    for (int r = 0; r < 16; ++r) {
        int kk = r * 4 + ty;
        float v = src[(size_t)kk * 1024 + tx];
        tile[kk][tx] = v;
        part += v;
    }
    csum[ty][tx] = part;
    __syncthreads();
    if (threadIdx.x < 64) {
        float s = csum[0][tx] + csum[1][tx] + csum[2][tx] + csum[3][tx];
        atomicAdd(&cy[b * 1024 + nt + tx], s);
    }
    int ky = threadIdx.x & 15;
    int ny = threadIdx.x >> 4;
#pragma unroll
    for (int r = 0; r < 4; ++r) {
        int nn = r * 16 + ny;
        unsigned b0 = __float_as_uint(tile[ky * 4 + 0][nn] + 8388608.0f);
        unsigned b1 = __float_as_uint(tile[ky * 4 + 1][nn] + 8388608.0f);
        unsigned b2 = __float_as_uint(tile[ky * 4 + 2][nn] + 8388608.0f);
        unsigned b3 = __float_as_uint(tile[ky * 4 + 3][nn] + 8388608.0f);
        unsigned p = ((b0 & 0xFFu) | ((b1 & 0xFFu) << 8) | ((b2 & 0xFFu) << 16) |
                      ((b3 & 0xFFu) << 24)) ^ 0x80808080u;
        *(unsigned*)&yt[((size_t)b << 20) + (size_t)(nt + nn) * 1024 + kt + ky * 4] = p;
    }
}

// ---- fused GEMM ----
__global__ __launch_bounds__(512, 2) void k_gemm(const float* __restrict__ xf,
                                                 const unsigned char* __restrict__ yt,
                                                 const float* __restrict__ cy,
                                                 float* __restrict__ out) {
    __shared__ __align__(16) unsigned char As[2][256 * 64];   // 32 KB, A i8 ring-2
    __shared__ __align__(16) unsigned char Bs[3][256 * 64];   // 48 KB, B i8 ring-3

    int bid = blockIdx.x;                         // 896 = 8 * 112, bijective XCD swz
    int wg  = (bid & 7) * 112 + (bid >> 3);
    int g   = wg >> 4;
    int t   = wg & 15;
    int m0  = (t >> 2) * 256, n0 = (t & 3) * 256;
    int b   = g & 7;

    int tid = threadIdx.x, lane = tid & 63, w = tid >> 6;
    int wm = w >> 2, wn = w & 3;                  // 2M x 4N wave grid

    // A stage: thread owns rows r0 (h0) / r0+128 (h1), 16-el chunk cg
    int r0   = tid >> 2;
    int cg   = tid & 3;
    int wkey = (tid >> 3) & 3;                    // (r0>>1)&3
    int wadr0 = r0 * 64 + ((cg ^ wkey) * 16);     // swizzled ds_write addr (h0)
    int wadr1 = wadr0 + 8192;                     // h1
    const float* Af0 = xf + (size_t)g * 1048576 + (size_t)(m0 + r0) * 1024 + cg * 16;
    const float* Af1 = Af0 + 131072;

    // B staging (verified): inverse-source swizzle, linear LDS dest
    size_t soff0 = (size_t)r0 * 1024 + (size_t)((cg ^ wkey) * 16);
    size_t soff1 = soff0 + 131072;
    int bdst0 = (tid & ~63) * 16;
    int bdst1 = 8192 + bdst0;
    const unsigned char* Bb = yt + ((size_t)b << 20) + (size_t)n0 * 1024;

    // fragment reads (verified): key=(lane>>1)&3; base + offset imms for rows
    int arow = lane & 31, hi = lane >> 5, key = (lane >> 1) & 3;
    int abase = (wm * 128 + arow) * 64;
    int bbase = (wn * 64 + arow) * 64;
    int c0 = (hi ^ key) * 16;
    int c1 = ((2 + hi) ^ key) * 16;

    v16i acc[4][2];
#pragma unroll
    for (int i = 0; i < 4; ++i)
#pragma unroll
        for (int j = 0; j < 2; ++j)
#pragma unroll
            for (int q = 0; q < 16; ++q) acc[i][j][q] = 0;

    v4i frA0, frA1, frA2, frA3;   // in-flight A h0 (16 VGPR)
    v4i frB0, frB1, frB2, frB3;   // in-flight A h1 (16 VGPR)
    float rs0 = 0.f, rs1 = 0.f;

#define SB0 __builtin_amdgcn_sched_barrier(0)
#define LGKM(N) asm volatile("s_waitcnt lgkmcnt(" #N ")" ::: "memory")
#define VMW(N)  asm volatile("s_waitcnt vmcnt(" #N ")" ::: "memory")
#define NOVM (void)0

#define LOADA_H0(KT2) do {                                                          \
    const float* _p = Af0 + (KT2) * 64;                                             \
    asm volatile("global_load_dwordx4 %0, %1, off"           : "=v"(frA0) : "v"(_p) : "memory"); \
    asm volatile("global_load_dwordx4 %0, %1, off offset:16" : "=v"(frA1) : "v"(_p) : "memory"); \
    asm volatile("global_load_dwordx4 %0, %1, off offset:32" : "=v"(frA2) : "v"(_p) : "memory"); \
    asm volatile("global_load_dwordx4 %0, %1, off offset:48" : "=v"(frA3) : "v"(_p) : "memory"); \
} while (0)
#define LOADA_H1(KT1) do {                                                          \
    const float* _p = Af1 + (KT1) * 64;                                             \
    asm volatile("global_load_dwordx4 %0, %1, off"           : "=v"(frB0) : "v"(_p) : "memory"); \
    asm volatile("global_load_dwordx4 %0, %1, off offset:16" : "=v"(frB1) : "v"(_p) : "memory"); \
    asm volatile("global_load_dwordx4 %0, %1, off offset:32" : "=v"(frB2) : "v"(_p) : "memory"); \
    asm volatile("global_load_dwordx4 %0, %1, off offset:48" : "=v"(frB3) : "v"(_p) : "memory"); \
} while (0)

#define PACK_H0(SAW) do {                                                           \
    unsigned q0 = pk(frA0, rs0), q1 = pk(frA1, rs0);                                \
    unsigned q2 = pk(frA2, rs0), q3 = pk(frA3, rs0);                                \
    v4i _w = { (int)q0, (int)q1, (int)q2, (int)q3 };                                \
    *(v4i*)&As[SAW][wadr0] = _w;                                                    \
} while (0)
#define PACK_H1(SAW) do {                                                           \
    unsigned q0 = pk(frB0, rs1), q1 = pk(frB1, rs1);                                \
    unsigned q2 = pk(frB2, rs1), q3 = pk(frB3, rs1);                                \
    v4i _w = { (int)q0, (int)q1, (int)q2, (int)q3 };                                \
    *(v4i*)&As[SAW][wadr1] = _w;                                                    \
} while (0)

#define STAGEB(SLOT, KT2) do {                                                      \
    GLOAD16(Bb + soff0 + (size_t)(KT2) * 64, &Bs[SLOT][bdst0]);                     \
    GLOAD16(Bb + soff1 + (size_t)(KT2) * 64, &Bs[SLOT][bdst1]);                     \
} while (0)

#define MFMA4(I, A0_, A1_, B0_, B1_) do {                 \
    __builtin_amdgcn_s_setprio(1);                        \
    acc[I][0]     = MFMA_I8(A0_, B0_, acc[I][0]);         \
    acc[I][1]     = MFMA_I8(A0_, B1_, acc[I][1]);         \
    acc[I + 1][0] = MFMA_I8(A1_, B0_, acc[I + 1][0]);     \
    acc[I + 1][1] = MFMA_I8(A1_, B1_, acc[I + 1][1]);     \
    __builtin_amdgcn_s_setprio(0);                        \
} while (0)

// 4 phases per K-tile. p reads are one phase ahead of the MFMA that uses them.
#define TILE(SA, SAW, SBr, SBW, KT, H1L, PCK, DOB, DOA, VMP3) do {                  \
    lds_cptr a0p = (lds_cptr)&As[SA][abase + c0];                                   \
    lds_cptr a1p = (lds_cptr)&As[SA][abase + c1];                                   \
    lds_cptr b0p = (lds_cptr)&Bs[SBr][bbase + c0];                                  \
    lds_cptr b1p = (lds_cptr)&Bs[SBr][bbase + c1];                                  \
    v4i fa0, fa1, fb0, fb1, ga0, ga1, ha0, ha1, hb0, hb1, ia0, ia1;                 \
    /* p0 */                                                                        \
    __builtin_amdgcn_s_barrier(); SB0;                                              \
    LDSR(fa0, a0p, 0);    LDSR(fa1, a0p, 2048);                                     \
    LDSR(fb0, b0p, 0);    LDSR(fb1, b0p, 2048);                                     \
    LDSR(ga0, a0p, 4096); LDSR(ga1, a0p, 6144);                                     \
    if (H1L) { LOADA_H1((KT) + 1); }                                                \
    LGKM(2); SB0;                                                                   \
    MFMA4(0, fa0, fa1, fb0, fb1);                                                   \
    /* p1 */                                                                        \
    __builtin_amdgcn_s_barrier(); SB0;                                              \
    LDSR(ha0, a1p, 0);    LDSR(ha1, a1p, 2048);                                     \
    LDSR(hb0, b1p, 0);    LDSR(hb1, b1p, 2048);                                     \
    VMW(4); SB0;                                                                    \
    if (PCK) { PACK_H0(SAW); }                                                      \
    LGKM(4); SB0;                                                                   \
    MFMA4(2, ga0, ga1, fb0, fb1);                                                   \
    /* p2 */                                                                        \
    __builtin_amdgcn_s_barrier(); SB0;                                              \
    LDSR(ia0, a1p, 4096); LDSR(ia1, a1p, 6144);                                     \
    if (DOB) { STAGEB(SBW, (KT) + 2); }                                             \
    LGKM(2); SB0;                                                                   \
    MFMA4(0, ha0, ha1, hb0, hb1);                                                   \
    /* p3 */                                                                        \
    __builtin_amdgcn_s_barrier(); SB0;                                              \
    VMP3; SB0;                                                                      \
    if (PCK) { PACK_H1(SAW); }                                                      \
    if (DOA) { LOADA_H0((KT) + 2); }                                                \
    LGKM(0); SB0;                                                                   \
    MFMA4(2, ia0, ia1, hb0, hb1);                                                   \
} while (0)

    // ---- prologue: A(0) fp32 in regs; B(0),B(1) staged; pack A(0)->slot0;
    //      issue A_h0(1); drain B(0) before first reads (vmcnt(6)).
    LOADA_H0(0); LOADA_H1(0); SB0;
    STAGEB(0, 0); STAGEB(1, 1); SB0;
    VMW(4); SB0;                 // A(0)x8 drained (B x4 younger)
    PACK_H0(0); PACK_H1(0);
    LOADA_H0(1); SB0;            // outstanding: B(0)2, B(1)2, Ah0(1)4
    VMW(6); SB0;                 // B(0) landed
    LGKM(0); SB0;                // slot0 pack writes done (barrier in p0 syncs waves)

    // ---- main loop: T = 0..11 (period-6 slot pattern), then 12..15 peeled
#pragma unroll 1
    for (int rr = 0; rr < 2; ++rr) {
        int KT = rr * 6;
        TILE(0, 1, 0, 2, (KT + 0), 1, 1, 1, 1, VMW(2));
        TILE(1, 0, 1, 0, (KT + 1), 1, 1, 1, 1, VMW(2));
        TILE(0, 1, 2, 1, (KT + 2), 1, 1, 1, 1, VMW(2));
        TILE(1, 0, 0, 2, (KT + 3), 1, 1, 1, 1, VMW(2));
        TILE(0, 1, 1, 0, (KT + 4), 1, 1, 1, 1, VMW(2));
        TILE(1, 0, 2, 1, (KT + 5), 1, 1, 1, 1, VMW(2));
    }
    TILE(0, 1, 0, 2, 12, 1, 1, 1, 1, VMW(2));
    TILE(1, 0, 1, 0, 13, 1, 1, 1, 1, VMW(2));
    TILE(0, 1, 2, 0, 14, 1, 1, 0, 0, VMW(0));   // packs tile 15; no new issues
    TILE(1, 0, 0, 0, 15, 0, 0, 0, 0, NOVM);     // pure drain
#undef TILE

    // ---- row sums: 4 chunk-lanes per row-half -> rxs (reuse As)
    rs0 += __shfl_xor(rs0, 1); rs0 += __shfl_xor(rs0, 2);
    rs1 += __shfl_xor(rs1, 1); rs1 += __shfl_xor(rs1, 2);
    float* rxs = (float*)&As[0][0];
    __syncthreads();
    if ((tid & 3) == 0) { rxs[r0] = rs0; rxs[r0 + 128] = rs1; }
    __syncthreads();

    // ---- epilogue: out = 7.5e-4 * (S' - 32*Rx + 66*Cy - 10813440)
    const float* cyp = cy + b * 1024 + n0 + wn * 64;
    float* og = out + (size_t)g * 1048576 + (size_t)(m0 + wm * 128) * 1024 + n0 + wn * 64;
    int col = lane & 31, r4 = hi * 4;
#pragma unroll
    for (int fi = 0; fi < 4; ++fi)
#pragma unroll
        for (int fj = 0; fj < 2; ++fj) {
            int cc = fj * 32 + col;
            float cv = cyp[cc];
            v16i v = acc[fi][fj];
#pragma unroll
            for (int q = 0; q < 16; ++q) {
                int rl = (q & 3) + 8 * (q >> 2) + r4;
                float rxv = rxs[wm * 128 + fi * 32 + rl];
                og[(size_t)(fi * 32 + rl) * 1024 + cc] =
                    7.5e-4f * ((float)v[q] - 32.0f * rxv + 66.0f * cv - 10813440.0f);
            }
        }
#undef LOADA_H0
#undef LOADA_H1
#undef PACK_H0
#undef PACK_H1
#undef STAGEB
#undef MFMA4
#undef LGKM
#undef VMW
#undef NOVM
#undef SB0
}

// ---- emergency fallback ----
__global__ void k_naive(const float* __restrict__ x, const float* __restrict__ y,
                        float* __restrict__ out) {
    int g = blockIdx.z, b = g & 7;
    int tx = threadIdx.x, ty = threadIdx.y;
    int m = blockIdx.y * 16 + ty, n = blockIdx.x * 16 + tx;
    __shared__ float a[16][17], bs[16][17];
    float s = 0.f;
    for (int kt = 0; kt < 64; ++kt) {
        a[ty][tx]  = x[(size_t)g * 1048576 + (size_t)m * 1024 + kt * 16 + tx];
        bs[ty][tx] = y[(size_t)b * 1048576 + (size_t)(kt * 16 + ty) * 1024 + n];
        __syncthreads();
#pragma unroll
        for (int j = 0; j < 16; ++j)
            s += ((a[ty][j] + 66.0f) * 0.03f) * ((bs[j][tx] - 160.0f) * 0.025f);
        __syncthreads();
    }
    out[(size_t)g * 1048576 + (size_t)m * 1024 + n] = s;
}

extern "C" void kernel_launch(void* const* d_in, const int* in_sizes, int n_in,
                              void* d_out, int out_size, void* d_ws, size_t ws_size,
                              hipStream_t stream) {
    const float* x = (const float*)d_in[0];
    const float* y = (const float*)d_in[1];
    float* out = (float*)d_out;

    const size_t CY_OFF = 0;                  // 32 KB
    const size_t YT_OFF = 262144;             // 8 MB i8 yt
    const size_t NEED   = YT_OFF + 8388608ull;

    if (ws_size >= NEED) {
        float* cy         = (float*)((char*)d_ws + CY_OFF);
        unsigned char* yt = (unsigned char*)((char*)d_ws + YT_OFF);
        hipMemsetAsync(cy, 0, 32768, stream);
        k_prep_y<<<2048, 256, 0, stream>>>(y, yt, cy);
        k_gemm<<<NG * 16, 512, 0, stream>>>(x, yt, cy, out);
    } else {
        dim3 grid(64, 64, NG), blk(16, 16);
        k_naive<<<grid, blk, 0, stream>>>(x, y, out);
    }
}